// Round 6
// baseline (306.740 us; speedup 1.0000x reference)
//
#include <hip/hip_runtime.h>
#include <hip/hip_fp16.h>
#include <math.h>

#define NWIN 8

typedef _Float16 f16x8 __attribute__((ext_vector_type(8)));
typedef float f32x4 __attribute__((ext_vector_type(4)));

__device__ __forceinline__ float eluf(float v) { return v > 0.f ? v : expm1f(v); }

// ---------------- degree count (in-degree) ----------------
__global__ __launch_bounds__(256) void deg_kernel(const int* __restrict__ dst,
                                                  int* __restrict__ counts, int E) {
    int e = blockIdx.x * 256 + threadIdx.x;
    if (e < E) atomicAdd(&counts[dst[e]], 1);
}

// ---------------- bucket alloc: padded offs via atomic bump ----------------
__global__ __launch_bounds__(256) void alloc_kernel(const int* __restrict__ counts,
                                                    int* __restrict__ gtotal,
                                                    int* __restrict__ offs,
                                                    int* __restrict__ cursor,
                                                    float* __restrict__ dinv, int n) {
    int i = blockIdx.x * 256 + threadIdx.x;
    if (i >= n) return;
    int c = counts[i];
    int pad = (c + 7) & ~7;              // bucket padded to x8 -> branch-free 8-wide gather
    int o = atomicAdd(gtotal, pad);
    offs[i] = o;
    cursor[i] = o;
    dinv[i] = rsqrtf((float)(c + 1));
}

// ---------------- fill csr_src with dummy index n (zero row) ----------------
__global__ __launch_bounds__(256) void fill_kernel(int* __restrict__ a, int v, int cap) {
    int i = blockIdx.x * 256 + threadIdx.x;
    if (i < cap) a[i] = v;
}

// ---------------- XCD-windowed scatter: window = blockIdx & 7 ----------------
__global__ __launch_bounds__(256) void scatter_kernel(const int* __restrict__ src,
                                                      const int* __restrict__ dst,
                                                      int* __restrict__ cursor,
                                                      int* __restrict__ csr_src,
                                                      int E, int winSize) {
    int win = blockIdx.x & (NWIN - 1);
    int group = blockIdx.x >> 3;
    int nGroups = gridDim.x >> 3;
    int lo = win * winSize, hi = lo + winSize;
    int stride = nGroups * 256;
    for (int e = group * 256 + threadIdx.x; e < E; e += stride) {
        int d = dst[e];
        if (d >= lo && d < hi) {
            int j = atomicAdd(&cursor[d], 1);
            csr_src[j] = src[e];
        }
    }
}

// ---------------- Ts0 planes = (x[N,128] @ w0[128,64]) * dinv[row], fp16 ----------------
// Split-fp16 (hi/lo) 3-term MFMA (proven R5). Output split into two dense planes:
// TA = features 0..31, TB = features 32..63 (each 3.2 MB -> fits per-XCD L2).
__global__ __launch_bounds__(256) void mm128_mfma(const float* __restrict__ H,
                                                  const float* __restrict__ W,
                                                  const float* __restrict__ dinv,
                                                  __half* __restrict__ TA,
                                                  __half* __restrict__ TB,
                                                  int n, int nTiles) {
    __shared__ _Float16 bhi[4][4][64][8];
    __shared__ _Float16 blo[4][4][64][8];
    int tid = threadIdx.x;
    for (int it = 0; it < 32; ++it) {
        int idx = it * 256 + tid;           // 8192 = 128 k * 64 n
        int k = idx >> 6, nn = idx & 63;
        float w = W[idx];
        _Float16 h = (_Float16)w;
        _Float16 l = (_Float16)(w - (float)h);
        int kt = k >> 5, kr = k & 31;
        int g = kr >> 3, j = kr & 7;
        int ct = nn >> 4, c = nn & 15;
        bhi[kt][ct][g * 16 + c][j] = h;
        blo[kt][ct][g * 16 + c][j] = l;
    }
    if (blockIdx.x == 0 && tid < 32) {
        TA[n * 32 + tid] = __float2half(0.f);
        TB[n * 32 + tid] = __float2half(0.f);
    }
    __syncthreads();

    int wave = blockIdx.x * 4 + (tid >> 6);
    if (wave >= nTiles) return;
    int lane = tid & 63;
    f16x8 Bh[4][4], Bl[4][4];
    #pragma unroll
    for (int kt = 0; kt < 4; ++kt)
        #pragma unroll
        for (int ct = 0; ct < 4; ++ct) {
            Bh[kt][ct] = *(const f16x8*)&bhi[kt][ct][lane][0];
            Bl[kt][ct] = *(const f16x8*)&blo[kt][ct][lane][0];
        }
    int row0 = wave * 16;
    int arow = row0 + (lane & 15);
    if (arow >= n) arow = n - 1;
    const float* hp = H + (size_t)arow * 128 + ((lane >> 4) << 3);
    f32x4 acc[4];
    #pragma unroll
    for (int ct = 0; ct < 4; ++ct) acc[ct] = (f32x4){0.f, 0.f, 0.f, 0.f};
    #pragma unroll
    for (int kt = 0; kt < 4; ++kt) {
        float4 p0 = *(const float4*)(hp + kt * 32);
        float4 p1 = *(const float4*)(hp + kt * 32 + 4);
        float v[8] = {p0.x, p0.y, p0.z, p0.w, p1.x, p1.y, p1.z, p1.w};
        f16x8 ah, al;
        #pragma unroll
        for (int j = 0; j < 8; ++j) {
            _Float16 h = (_Float16)v[j];
            ah[j] = h;
            al[j] = (_Float16)(v[j] - (float)h);
        }
        #pragma unroll
        for (int ct = 0; ct < 4; ++ct) {
            acc[ct] = __builtin_amdgcn_mfma_f32_16x16x32_f16(ah, Bh[kt][ct], acc[ct], 0, 0, 0);
            acc[ct] = __builtin_amdgcn_mfma_f32_16x16x32_f16(al, Bh[kt][ct], acc[ct], 0, 0, 0);
            acc[ct] = __builtin_amdgcn_mfma_f32_16x16x32_f16(ah, Bl[kt][ct], acc[ct], 0, 0, 0);
        }
    }
    int rbase = row0 + ((lane >> 4) << 2);
    int cbase = lane & 15;
    #pragma unroll
    for (int r = 0; r < 4; ++r) {
        int row = rbase + r;
        if (row < n) {
            float d = dinv[row];
            #pragma unroll
            for (int ct = 0; ct < 4; ++ct) {
                int col = ct * 16 + cbase;
                __half* P = (col < 32) ? TA : TB;
                P[row * 32 + (col & 31)] = __float2half(acc[ct][r] * d);
            }
        }
    }
}

// ---------------- pass A: aggregate plane-lo into fp32 partials ----------------
// 16-lane group per node, lane = 2 features. Plane (3.2 MB) is L2-resident;
// csr reads and agg writes are non-temporal so they don't evict it.
__global__ __launch_bounds__(256) void gatherA_kernel(const __half* __restrict__ P,
                                                      const int* __restrict__ offs,
                                                      const int* __restrict__ cnt,
                                                      const int* __restrict__ csr_src,
                                                      float* __restrict__ agg, int n) {
    int t = blockIdx.x * 256 + threadIdx.x;
    int node = t >> 4, l = t & 15;
    if (node >= n) return;
    const __half2* P2 = (const __half2*)P;
    float2 sv = __half22float2(P2[node * 16 + l]);     // self term
    float ax0 = sv.x, ay0 = sv.y;
    float ax1 = 0, ay1 = 0, ax2 = 0, ay2 = 0, ax3 = 0, ay3 = 0;
    int e0 = offs[node];
    int e1 = e0 + ((cnt[node] + 7) & ~7);
    #pragma unroll 1
    for (int e = e0; e < e1; e += 8) {
        int s0 = __builtin_nontemporal_load(csr_src + e);
        int s1 = __builtin_nontemporal_load(csr_src + e + 1);
        int s2 = __builtin_nontemporal_load(csr_src + e + 2);
        int s3 = __builtin_nontemporal_load(csr_src + e + 3);
        int s4 = __builtin_nontemporal_load(csr_src + e + 4);
        int s5 = __builtin_nontemporal_load(csr_src + e + 5);
        int s6 = __builtin_nontemporal_load(csr_src + e + 6);
        int s7 = __builtin_nontemporal_load(csr_src + e + 7);
        float2 v0 = __half22float2(P2[s0 * 16 + l]);
        float2 v1 = __half22float2(P2[s1 * 16 + l]);
        float2 v2 = __half22float2(P2[s2 * 16 + l]);
        float2 v3 = __half22float2(P2[s3 * 16 + l]);
        float2 v4 = __half22float2(P2[s4 * 16 + l]);
        float2 v5 = __half22float2(P2[s5 * 16 + l]);
        float2 v6 = __half22float2(P2[s6 * 16 + l]);
        float2 v7 = __half22float2(P2[s7 * 16 + l]);
        ax0 += v0.x + v4.x;  ay0 += v0.y + v4.y;
        ax1 += v1.x + v5.x;  ay1 += v1.y + v5.y;
        ax2 += v2.x + v6.x;  ay2 += v2.y + v6.y;
        ax3 += v3.x + v7.x;  ay3 += v3.y + v7.y;
    }
    float rx = (ax0 + ax1) + (ax2 + ax3);
    float ry = (ay0 + ay1) + (ay2 + ay3);
    __builtin_nontemporal_store(rx, agg + node * 32 + 2 * l);
    __builtin_nontemporal_store(ry, agg + node * 32 + 2 * l + 1);
}

// ---------------- pass B: aggregate plane-hi + finish (ELU) + next-layer MFMA matmul ----------------
// Block = 64 nodes. Phase 1: 16-lane groups gather plane-hi, combine with pass-A
// partials, ELU -> rowbuf. Phase 2: each wave does a 16-node tile of h @ Wn via
// 3-term split-fp16 MFMA (kills the 16 KB-per-node LDS W reads).
__global__ __launch_bounds__(256, 4) void gatherB_mm(const __half* __restrict__ PB,
                                                     const float* __restrict__ agg,
                                                     const int* __restrict__ offs,
                                                     const int* __restrict__ cnt,
                                                     const int* __restrict__ csr_src,
                                                     const float* __restrict__ dinv,
                                                     const float* __restrict__ bias,
                                                     const float* __restrict__ Wn,
                                                     __half* __restrict__ outA,
                                                     __half* __restrict__ outB, int n) {
    __shared__ _Float16 bhi[2][4][64][8];   // 8 KB
    __shared__ _Float16 blo[2][4][64][8];   // 8 KB
    __shared__ float rowbuf[64][68];        // 17.4 KB, pad 68 -> even bank-quads
    int tid = threadIdx.x;
    for (int it = 0; it < 16; ++it) {
        int idx = it * 256 + tid;           // 4096 = 64 k * 64 n
        int k = idx >> 6, nn = idx & 63;
        float w = Wn[idx];
        _Float16 h = (_Float16)w;
        _Float16 lo = (_Float16)(w - (float)h);
        int kt = k >> 5, kr = k & 31;
        int g = kr >> 3, j = kr & 7;
        int ct = nn >> 4, c = nn & 15;
        bhi[kt][ct][g * 16 + c][j] = h;
        blo[kt][ct][g * 16 + c][j] = lo;
    }
    if (blockIdx.x == 0 && tid < 32) {
        outA[n * 32 + tid] = __float2half(0.f);
        outB[n * 32 + tid] = __float2half(0.f);
    }
    int g16 = tid >> 4, l = tid & 15;
    int nodebase = blockIdx.x * 64;
    const __half2* P2 = (const __half2*)PB;
    #pragma unroll 1
    for (int q = 0; q < 4; ++q) {
        int ln = 4 * g16 + q;
        int node = nodebase + ln;
        float h0 = 0.f, h1 = 0.f, h2 = 0.f, h3 = 0.f;
        if (node < n) {
            float2 sv = __half22float2(P2[node * 16 + l]);
            float ax0 = sv.x, ay0 = sv.y;
            float ax1 = 0, ay1 = 0, ax2 = 0, ay2 = 0, ax3 = 0, ay3 = 0;
            int e0 = offs[node];
            int e1 = e0 + ((cnt[node] + 7) & ~7);
            #pragma unroll 1
            for (int e = e0; e < e1; e += 8) {
                int s0 = __builtin_nontemporal_load(csr_src + e);
                int s1 = __builtin_nontemporal_load(csr_src + e + 1);
                int s2 = __builtin_nontemporal_load(csr_src + e + 2);
                int s3 = __builtin_nontemporal_load(csr_src + e + 3);
                int s4 = __builtin_nontemporal_load(csr_src + e + 4);
                int s5 = __builtin_nontemporal_load(csr_src + e + 5);
                int s6 = __builtin_nontemporal_load(csr_src + e + 6);
                int s7 = __builtin_nontemporal_load(csr_src + e + 7);
                float2 v0 = __half22float2(P2[s0 * 16 + l]);
                float2 v1 = __half22float2(P2[s1 * 16 + l]);
                float2 v2 = __half22float2(P2[s2 * 16 + l]);
                float2 v3 = __half22float2(P2[s3 * 16 + l]);
                float2 v4 = __half22float2(P2[s4 * 16 + l]);
                float2 v5 = __half22float2(P2[s5 * 16 + l]);
                float2 v6 = __half22float2(P2[s6 * 16 + l]);
                float2 v7 = __half22float2(P2[s7 * 16 + l]);
                ax0 += v0.x + v4.x;  ay0 += v0.y + v4.y;
                ax1 += v1.x + v5.x;  ay1 += v1.y + v5.y;
                ax2 += v2.x + v6.x;  ay2 += v2.y + v6.y;
                ax3 += v3.x + v7.x;  ay3 += v3.y + v7.y;
            }
            float shx = (ax0 + ax1) + (ax2 + ax3);
            float shy = (ay0 + ay1) + (ay2 + ay3);
            float a0 = __builtin_nontemporal_load(agg + node * 32 + 2 * l);
            float a1 = __builtin_nontemporal_load(agg + node * 32 + 2 * l + 1);
            float di = dinv[node];
            float2 bl = *(const float2*)(bias + 2 * l);
            float2 bh = *(const float2*)(bias + 32 + 2 * l);
            h0 = eluf(a0 * di + bl.x);
            h1 = eluf(a1 * di + bl.y);
            h2 = eluf(shx * di + bh.x);
            h3 = eluf(shy * di + bh.y);
        }
        *(float2*)&rowbuf[ln][2 * l] = make_float2(h0, h1);
        *(float2*)&rowbuf[ln][32 + 2 * l] = make_float2(h2, h3);
    }
    __syncthreads();

    // MFMA phase: wave wv owns local rows 16*wv .. 16*wv+15
    int wv = tid >> 6, lane = tid & 63;
    f16x8 Bh[2][4], Bl[2][4];
    #pragma unroll
    for (int kt = 0; kt < 2; ++kt)
        #pragma unroll
        for (int ct = 0; ct < 4; ++ct) {
            Bh[kt][ct] = *(const f16x8*)&bhi[kt][ct][lane][0];
            Bl[kt][ct] = *(const f16x8*)&blo[kt][ct][lane][0];
        }
    int trow = wv * 16 + (lane & 15);
    int kb = (lane >> 4) << 3;
    f32x4 acc[4];
    #pragma unroll
    for (int ct = 0; ct < 4; ++ct) acc[ct] = (f32x4){0.f, 0.f, 0.f, 0.f};
    #pragma unroll
    for (int kt = 0; kt < 2; ++kt) {
        float4 p0 = *(const float4*)&rowbuf[trow][kt * 32 + kb];
        float4 p1 = *(const float4*)&rowbuf[trow][kt * 32 + kb + 4];
        float v[8] = {p0.x, p0.y, p0.z, p0.w, p1.x, p1.y, p1.z, p1.w};
        f16x8 ah, al;
        #pragma unroll
        for (int j = 0; j < 8; ++j) {
            _Float16 h = (_Float16)v[j];
            ah[j] = h;
            al[j] = (_Float16)(v[j] - (float)h);
        }
        #pragma unroll
        for (int ct = 0; ct < 4; ++ct) {
            acc[ct] = __builtin_amdgcn_mfma_f32_16x16x32_f16(ah, Bh[kt][ct], acc[ct], 0, 0, 0);
            acc[ct] = __builtin_amdgcn_mfma_f32_16x16x32_f16(al, Bh[kt][ct], acc[ct], 0, 0, 0);
            acc[ct] = __builtin_amdgcn_mfma_f32_16x16x32_f16(ah, Bl[kt][ct], acc[ct], 0, 0, 0);
        }
    }
    int rb = wv * 16 + ((lane >> 4) << 2);
    int cb = lane & 15;
    #pragma unroll
    for (int r = 0; r < 4; ++r) {
        int node = nodebase + rb + r;
        if (node < n) {
            float d = dinv[node];
            #pragma unroll
            for (int ct = 0; ct < 4; ++ct) {
                int col = ct * 16 + cb;
                __half* P = (col < 32) ? outA : outB;
                P[node * 32 + (col & 31)] = __float2half(acc[ct][r] * d);
            }
        }
    }
}

// ---------------- final pass B: gather plane-hi + ELU + FC(64->16) MFMA + softmax ----------------
__global__ __launch_bounds__(256, 4) void gatherB_fc(const __half* __restrict__ PB,
                                                     const float* __restrict__ agg,
                                                     const int* __restrict__ offs,
                                                     const int* __restrict__ cnt,
                                                     const int* __restrict__ csr_src,
                                                     const float* __restrict__ dinv,
                                                     const float* __restrict__ bias,
                                                     const float* __restrict__ fcw,
                                                     const float* __restrict__ fcb,
                                                     float* __restrict__ out, int n) {
    __shared__ _Float16 bhi[2][64][8];      // 2 KB
    __shared__ _Float16 blo[2][64][8];
    __shared__ float rowbuf[64][68];
    int tid = threadIdx.x;
    for (int it = 0; it < 4; ++it) {
        int idx = it * 256 + tid;           // 1024 = 64 k * 16 j
        int k = idx >> 4, j16 = idx & 15;
        float w = fcw[idx];
        _Float16 h = (_Float16)w;
        _Float16 lo = (_Float16)(w - (float)h);
        int kt = k >> 5, kr = k & 31;
        int g = kr >> 3, j = kr & 7;
        bhi[kt][g * 16 + j16][j] = h;
        blo[kt][g * 16 + j16][j] = lo;
    }
    int g16 = tid >> 4, l = tid & 15;
    int nodebase = blockIdx.x * 64;
    const __half2* P2 = (const __half2*)PB;
    #pragma unroll 1
    for (int q = 0; q < 4; ++q) {
        int ln = 4 * g16 + q;
        int node = nodebase + ln;
        float h0 = 0.f, h1 = 0.f, h2 = 0.f, h3 = 0.f;
        if (node < n) {
            float2 sv = __half22float2(P2[node * 16 + l]);
            float ax0 = sv.x, ay0 = sv.y;
            float ax1 = 0, ay1 = 0, ax2 = 0, ay2 = 0, ax3 = 0, ay3 = 0;
            int e0 = offs[node];
            int e1 = e0 + ((cnt[node] + 7) & ~7);
            #pragma unroll 1
            for (int e = e0; e < e1; e += 8) {
                int s0 = __builtin_nontemporal_load(csr_src + e);
                int s1 = __builtin_nontemporal_load(csr_src + e + 1);
                int s2 = __builtin_nontemporal_load(csr_src + e + 2);
                int s3 = __builtin_nontemporal_load(csr_src + e + 3);
                int s4 = __builtin_nontemporal_load(csr_src + e + 4);
                int s5 = __builtin_nontemporal_load(csr_src + e + 5);
                int s6 = __builtin_nontemporal_load(csr_src + e + 6);
                int s7 = __builtin_nontemporal_load(csr_src + e + 7);
                float2 v0 = __half22float2(P2[s0 * 16 + l]);
                float2 v1 = __half22float2(P2[s1 * 16 + l]);
                float2 v2 = __half22float2(P2[s2 * 16 + l]);
                float2 v3 = __half22float2(P2[s3 * 16 + l]);
                float2 v4 = __half22float2(P2[s4 * 16 + l]);
                float2 v5 = __half22float2(P2[s5 * 16 + l]);
                float2 v6 = __half22float2(P2[s6 * 16 + l]);
                float2 v7 = __half22float2(P2[s7 * 16 + l]);
                ax0 += v0.x + v4.x;  ay0 += v0.y + v4.y;
                ax1 += v1.x + v5.x;  ay1 += v1.y + v5.y;
                ax2 += v2.x + v6.x;  ay2 += v2.y + v6.y;
                ax3 += v3.x + v7.x;  ay3 += v3.y + v7.y;
            }
            float shx = (ax0 + ax1) + (ax2 + ax3);
            float shy = (ay0 + ay1) + (ay2 + ay3);
            float a0 = __builtin_nontemporal_load(agg + node * 32 + 2 * l);
            float a1 = __builtin_nontemporal_load(agg + node * 32 + 2 * l + 1);
            float di = dinv[node];
            float2 bl = *(const float2*)(bias + 2 * l);
            float2 bh = *(const float2*)(bias + 32 + 2 * l);
            h0 = eluf(a0 * di + bl.x);
            h1 = eluf(a1 * di + bl.y);
            h2 = eluf(shx * di + bh.x);
            h3 = eluf(shy * di + bh.y);
        }
        *(float2*)&rowbuf[ln][2 * l] = make_float2(h0, h1);
        *(float2*)&rowbuf[ln][32 + 2 * l] = make_float2(h2, h3);
    }
    __syncthreads();

    int wv = tid >> 6, lane = tid & 63;
    f16x8 Bh[2], Bl[2];
    #pragma unroll
    for (int kt = 0; kt < 2; ++kt) {
        Bh[kt] = *(const f16x8*)&bhi[kt][lane][0];
        Bl[kt] = *(const f16x8*)&blo[kt][lane][0];
    }
    int trow = wv * 16 + (lane & 15);
    int kb = (lane >> 4) << 3;
    f32x4 acc = (f32x4){0.f, 0.f, 0.f, 0.f};
    #pragma unroll
    for (int kt = 0; kt < 2; ++kt) {
        float4 p0 = *(const float4*)&rowbuf[trow][kt * 32 + kb];
        float4 p1 = *(const float4*)&rowbuf[trow][kt * 32 + kb + 4];
        float v[8] = {p0.x, p0.y, p0.z, p0.w, p1.x, p1.y, p1.z, p1.w};
        f16x8 ah, al;
        #pragma unroll
        for (int j = 0; j < 8; ++j) {
            _Float16 h = (_Float16)v[j];
            ah[j] = h;
            al[j] = (_Float16)(v[j] - (float)h);
        }
        acc = __builtin_amdgcn_mfma_f32_16x16x32_f16(ah, Bh[kt], acc, 0, 0, 0);
        acc = __builtin_amdgcn_mfma_f32_16x16x32_f16(al, Bh[kt], acc, 0, 0, 0);
        acc = __builtin_amdgcn_mfma_f32_16x16x32_f16(ah, Bl[kt], acc, 0, 0, 0);
    }
    // C layout: row R = wv*16 + (lane>>4)*4 + r (16 lanes share R), col = lane&15.
    float bj = fcb[lane & 15];
    #pragma unroll
    for (int r = 0; r < 4; ++r) {
        float o = acc[r] + bj;
        float m = o;
        #pragma unroll
        for (int d = 8; d; d >>= 1) m = fmaxf(m, __shfl_xor(m, d, 64));
        float ex = expf(o - m);
        float s = ex;
        #pragma unroll
        for (int d = 8; d; d >>= 1) s += __shfl_xor(s, d, 64);
        int node = nodebase + wv * 16 + ((lane >> 4) << 2) + r;
        if (node < n) out[(size_t)node * 16 + (lane & 15)] = ex / s;
    }
}

extern "C" void kernel_launch(void* const* d_in, const int* in_sizes, int n_in,
                              void* d_out, int out_size, void* d_ws, size_t ws_size,
                              hipStream_t stream) {
    const float* x   = (const float*)d_in[0];
    const int*   ei  = (const int*)d_in[1];
    const float* w0  = (const float*)d_in[2];
    const float* b0  = (const float*)d_in[3];
    const float* w1  = (const float*)d_in[4];
    const float* b1  = (const float*)d_in[5];
    const float* w2  = (const float*)d_in[6];
    const float* b2  = (const float*)d_in[7];
    const float* fcw = (const float*)d_in[8];
    const float* fcb = (const float*)d_in[9];
    float* out = (float*)d_out;

    const int N = in_sizes[0] / 128;
    const int E = in_sizes[1] / 2;
    const int* src = ei;
    const int* dst = ei + E;
    const int csr_cap = E + 8 * N + 8;

    char* p = (char*)d_ws;
    auto take = [&](size_t bytes) {
        char* q = p;
        p += (bytes + 255) & ~(size_t)255;
        return q;
    };
    int*    counts  = (int*)take((size_t)(N + 1) * 4);  // counts[N] = gtotal
    int*    gtotal  = counts + N;
    int*    offs    = (int*)take((size_t)N * 4);
    int*    cursor  = (int*)take((size_t)N * 4);
    float*  dinv    = (float*)take((size_t)N * 4);
    int*    csr_src = (int*)take((size_t)csr_cap * 4);
    float*  aggbuf  = (float*)take((size_t)N * 32 * 4);
    __half* TA0     = (__half*)take((size_t)(N + 1) * 32 * 2);
    __half* TB0     = (__half*)take((size_t)(N + 1) * 32 * 2);
    __half* TA1     = (__half*)take((size_t)(N + 1) * 32 * 2);
    __half* TB1     = (__half*)take((size_t)(N + 1) * 32 * 2);

    hipMemsetAsync(counts, 0, (size_t)(N + 1) * 4, stream);

    deg_kernel<<<(E + 255) / 256, 256, 0, stream>>>(dst, counts, E);
    alloc_kernel<<<(N + 255) / 256, 256, 0, stream>>>(counts, gtotal, offs, cursor, dinv, N);
    fill_kernel<<<(csr_cap + 255) / 256, 256, 0, stream>>>(csr_src, N, csr_cap);
    int winSize = (N + NWIN - 1) / NWIN;
    scatter_kernel<<<1024, 256, 0, stream>>>(src, dst, cursor, csr_src, E, winSize);

    int nTiles = (N + 15) / 16;
    int gA_grid = (N + 15) / 16;     // 16 nodes / block
    int gB_grid = (N + 63) / 64;     // 64 nodes / block

    mm128_mfma<<<(nTiles + 3) / 4, 256, 0, stream>>>(x, w0, dinv, TA0, TB0, N, nTiles);

    // layer 1
    gatherA_kernel<<<gA_grid, 256, 0, stream>>>(TA0, offs, counts, csr_src, aggbuf, N);
    gatherB_mm<<<gB_grid, 256, 0, stream>>>(TB0, aggbuf, offs, counts, csr_src,
                                            dinv, b0, w1, TA1, TB1, N);
    // layer 2
    gatherA_kernel<<<gA_grid, 256, 0, stream>>>(TA1, offs, counts, csr_src, aggbuf, N);
    gatherB_mm<<<gB_grid, 256, 0, stream>>>(TB1, aggbuf, offs, counts, csr_src,
                                            dinv, b1, w2, TA0, TB0, N);
    // final layer + FC + softmax
    gatherA_kernel<<<gA_grid, 256, 0, stream>>>(TA0, offs, counts, csr_src, aggbuf, N);
    gatherB_fc<<<gB_grid, 256, 0, stream>>>(TB0, aggbuf, offs, counts, csr_src,
                                            dinv, b2, fcw, fcb, out, N);
}

// Round 10
// 257.413 us; speedup vs baseline: 1.1916x; 1.1916x over previous
//
#include <hip/hip_runtime.h>
#include <hip/hip_fp16.h>
#include <math.h>

#define NWIN 8

typedef _Float16 f16x8 __attribute__((ext_vector_type(8)));
typedef float f32x4 __attribute__((ext_vector_type(4)));
typedef int i32x4 __attribute__((ext_vector_type(4)));
typedef unsigned int u32x4 __attribute__((ext_vector_type(4)));

__device__ __forceinline__ float eluf(float v) { return v > 0.f ? v : expm1f(v); }

// unpack one u32 (2 x fp16) -> float2; address-of-scalar is legal
__device__ __forceinline__ float2 cvt2(unsigned int w) {
    __half2 h = *reinterpret_cast<const __half2*>(&w);
    return __half22float2(h);
}

// ---------------- degree count (in-degree) ----------------
__global__ __launch_bounds__(256) void deg_kernel(const int* __restrict__ dst,
                                                  int* __restrict__ counts, int E) {
    int e = blockIdx.x * 256 + threadIdx.x;
    if (e < E) atomicAdd(&counts[dst[e]], 1);
}

// ---------------- bucket alloc + pad fill ----------------
__global__ __launch_bounds__(256) void alloc_kernel(const int* __restrict__ counts,
                                                    int* __restrict__ gtotal,
                                                    int* __restrict__ offs,
                                                    int* __restrict__ cursor,
                                                    float* __restrict__ dinv,
                                                    int* __restrict__ csr_src, int n) {
    int i = blockIdx.x * 256 + threadIdx.x;
    if (i >= n) return;
    int c = counts[i];
    int pad = (c + 7) & ~7;
    int o = atomicAdd(gtotal, pad);
    offs[i] = o;
    cursor[i] = o;
    dinv[i] = rsqrtf((float)(c + 1));
    for (int j = c; j < pad; ++j) csr_src[o + j] = n;
}

// ---------------- XCD-windowed scatter: window = blockIdx & 7 ----------------
__global__ __launch_bounds__(256) void scatter_kernel(const int* __restrict__ src,
                                                      const int* __restrict__ dst,
                                                      int* __restrict__ cursor,
                                                      int* __restrict__ csr_src,
                                                      int E, int winSize) {
    int win = blockIdx.x & (NWIN - 1);
    int group = blockIdx.x >> 3;
    int nGroups = gridDim.x >> 3;
    int lo = win * winSize, hi = lo + winSize;
    int stride = nGroups * 256;
    for (int e = group * 256 + threadIdx.x; e < E; e += stride) {
        int d = dst[e];
        if (d >= lo && d < hi) {
            int j = atomicAdd(&cursor[d], 1);
            csr_src[j] = src[e];
        }
    }
}

// ---------------- Ts0 = (x[N,128] @ w0[128,64]) * dinv[row], fp16, via MFMA ----------------
// Split-fp16 (hi/lo) 3-term MFMA: acc = Ah*Bh + Al*Bh + Ah*Bl.
__global__ __launch_bounds__(256) void mm128_mfma(const float* __restrict__ H,
                                                  const float* __restrict__ W,
                                                  const float* __restrict__ dinv,
                                                  __half* __restrict__ T, int n, int nTiles) {
    __shared__ _Float16 bhi[4][4][64][8];
    __shared__ _Float16 blo[4][4][64][8];
    int tid = threadIdx.x;
    for (int it = 0; it < 32; ++it) {
        int idx = it * 256 + tid;           // 8192 = 128 k * 64 n
        int k = idx >> 6, nn = idx & 63;
        float w = W[idx];
        _Float16 h = (_Float16)w;
        _Float16 l = (_Float16)(w - (float)h);
        int kt = k >> 5, kr = k & 31;
        int g = kr >> 3, j = kr & 7;
        int ct = nn >> 4, c = nn & 15;
        bhi[kt][ct][g * 16 + c][j] = h;
        blo[kt][ct][g * 16 + c][j] = l;
    }
    if (blockIdx.x == 0 && tid < 64) T[(size_t)n * 64 + tid] = __float2half(0.f);
    __syncthreads();

    int wave = blockIdx.x * 4 + (tid >> 6);
    if (wave >= nTiles) return;
    int lane = tid & 63;
    f16x8 Bh[4][4], Bl[4][4];
    #pragma unroll
    for (int kt = 0; kt < 4; ++kt)
        #pragma unroll
        for (int ct = 0; ct < 4; ++ct) {
            Bh[kt][ct] = *(const f16x8*)&bhi[kt][ct][lane][0];
            Bl[kt][ct] = *(const f16x8*)&blo[kt][ct][lane][0];
        }
    int row0 = wave * 16;
    int arow = row0 + (lane & 15);
    if (arow >= n) arow = n - 1;
    const float* hp = H + (size_t)arow * 128 + ((lane >> 4) << 3);
    f32x4 acc[4];
    #pragma unroll
    for (int ct = 0; ct < 4; ++ct) acc[ct] = (f32x4){0.f, 0.f, 0.f, 0.f};
    #pragma unroll
    for (int kt = 0; kt < 4; ++kt) {
        float4 p0 = *(const float4*)(hp + kt * 32);
        float4 p1 = *(const float4*)(hp + kt * 32 + 4);
        float v[8] = {p0.x, p0.y, p0.z, p0.w, p1.x, p1.y, p1.z, p1.w};
        f16x8 ah, al;
        #pragma unroll
        for (int j = 0; j < 8; ++j) {
            _Float16 h = (_Float16)v[j];
            ah[j] = h;
            al[j] = (_Float16)(v[j] - (float)h);
        }
        #pragma unroll
        for (int ct = 0; ct < 4; ++ct) {
            acc[ct] = __builtin_amdgcn_mfma_f32_16x16x32_f16(ah, Bh[kt][ct], acc[ct], 0, 0, 0);
            acc[ct] = __builtin_amdgcn_mfma_f32_16x16x32_f16(al, Bh[kt][ct], acc[ct], 0, 0, 0);
            acc[ct] = __builtin_amdgcn_mfma_f32_16x16x32_f16(ah, Bl[kt][ct], acc[ct], 0, 0, 0);
        }
    }
    int rbase = row0 + ((lane >> 4) << 2);
    int cbase = lane & 15;
    #pragma unroll
    for (int r = 0; r < 4; ++r) {
        int row = rbase + r;
        if (row < n) {
            float d = dinv[row];
            #pragma unroll
            for (int ct = 0; ct < 4; ++ct)
                T[(size_t)row * 64 + ct * 16 + cbase] = __float2half(acc[ct][r] * d);
        }
    }
}

// ---------------- fused agg + next-layer MFMA matmul ----------------
// Block = 512 threads = 64 nodes. Gather: 8-lane group per node, lane loads
// 16 B (u32x4 = 8 fp16 features) -> 8-edge unroll = 64 rows in flight/wave.
// MFMA phase: 8 waves cover 4 row-tiles x 2 col-halves of h @ Wn.
__global__ __launch_bounds__(512, 4) void agg_mm(const __half* __restrict__ T,
                                                 const int* __restrict__ offs,
                                                 const int* __restrict__ cnt,
                                                 const int* __restrict__ csr_src,
                                                 const float* __restrict__ dinv,
                                                 const float* __restrict__ bias,
                                                 const float* __restrict__ Wn,
                                                 __half* __restrict__ out, int n) {
    __shared__ _Float16 bhi[2][4][64][8];   // 8 KB
    __shared__ _Float16 blo[2][4][64][8];   // 8 KB
    __shared__ float rowbuf[64][68];        // 17.4 KB
    int tid = threadIdx.x;
    for (int it = 0; it < 8; ++it) {
        int idx = it * 512 + tid;           // 4096 = 64 k * 64 n
        int k = idx >> 6, nn = idx & 63;
        float w = Wn[idx];
        _Float16 h = (_Float16)w;
        _Float16 lo = (_Float16)(w - (float)h);
        int kt = k >> 5, kr = k & 31;
        int g = kr >> 3, j = kr & 7;
        int ct = nn >> 4, c = nn & 15;
        bhi[kt][ct][g * 16 + c][j] = h;
        blo[kt][ct][g * 16 + c][j] = lo;
    }
    if (blockIdx.x == 0 && tid < 64) out[(size_t)n * 64 + tid] = __float2half(0.f);

    int grp = tid >> 3;          // local node 0..63
    int l8 = tid & 7;            // 16B slice of the row
    int node = blockIdx.x * 64 + grp;
    float hA[4] = {0.f, 0.f, 0.f, 0.f};
    float hB[4] = {0.f, 0.f, 0.f, 0.f};
    if (node < n) {
        const u32x4* T4 = (const u32x4*)T;
        float ax[8] = {0,0,0,0,0,0,0,0};
        float ay[8] = {0,0,0,0,0,0,0,0};
        {   // self term
            u32x4 q = T4[node * 8 + l8];
            #pragma unroll
            for (int u = 0; u < 4; ++u) {
                float2 f = cvt2(q[u]);
                ax[u] += f.x; ax[u + 4] += f.y;
            }
        }
        int e0 = offs[node];
        int e1 = e0 + ((cnt[node] + 7) & ~7);
        #pragma unroll 1
        for (int e = e0; e < e1; e += 8) {
            i32x4 sa = __builtin_nontemporal_load((const i32x4*)(csr_src + e));
            i32x4 sb = __builtin_nontemporal_load((const i32x4*)(csr_src + e + 4));
            u32x4 q0 = T4[sa.x * 8 + l8];
            u32x4 q1 = T4[sa.y * 8 + l8];
            u32x4 q2 = T4[sa.z * 8 + l8];
            u32x4 q3 = T4[sa.w * 8 + l8];
            u32x4 q4 = T4[sb.x * 8 + l8];
            u32x4 q5 = T4[sb.y * 8 + l8];
            u32x4 q6 = T4[sb.z * 8 + l8];
            u32x4 q7 = T4[sb.w * 8 + l8];
            #pragma unroll
            for (int u = 0; u < 4; ++u) {
                float2 f0 = cvt2(q0[u]);
                float2 f1 = cvt2(q1[u]);
                float2 f2 = cvt2(q2[u]);
                float2 f3 = cvt2(q3[u]);
                float2 f4 = cvt2(q4[u]);
                float2 f5 = cvt2(q5[u]);
                float2 f6 = cvt2(q6[u]);
                float2 f7 = cvt2(q7[u]);
                ax[u]     += (f0.x + f1.x) + (f2.x + f3.x);
                ay[u]     += (f4.x + f5.x) + (f6.x + f7.x);
                ax[u + 4] += (f0.y + f1.y) + (f2.y + f3.y);
                ay[u + 4] += (f4.y + f5.y) + (f6.y + f7.y);
            }
        }
        float di = dinv[node];
        float4 b0 = *(const float4*)(bias + l8 * 8);
        float4 b1 = *(const float4*)(bias + l8 * 8 + 4);
        float bb[8] = {b0.x, b0.y, b0.z, b0.w, b1.x, b1.y, b1.z, b1.w};
        #pragma unroll
        for (int u = 0; u < 4; ++u) {
            hA[u] = eluf((ax[u] + ay[u]) * di + bb[2 * u]);
            hB[u] = eluf((ax[u + 4] + ay[u + 4]) * di + bb[2 * u + 1]);
        }
    }
    float4 r0 = make_float4(hA[0], hB[0], hA[1], hB[1]);
    float4 r1 = make_float4(hA[2], hB[2], hA[3], hB[3]);
    *(float4*)&rowbuf[grp][l8 * 8] = r0;
    *(float4*)&rowbuf[grp][l8 * 8 + 4] = r1;
    __syncthreads();

    // MFMA phase: wave wv -> row-tile (wv>>1), col-half (wv&1)
    int wv = tid >> 6, lane = tid & 63;
    int tile = wv >> 1, ct0 = (wv & 1) * 2;
    f16x8 Bh[2][2], Bl[2][2];
    #pragma unroll
    for (int kt = 0; kt < 2; ++kt)
        #pragma unroll
        for (int c2 = 0; c2 < 2; ++c2) {
            Bh[kt][c2] = *(const f16x8*)&bhi[kt][ct0 + c2][lane][0];
            Bl[kt][c2] = *(const f16x8*)&blo[kt][ct0 + c2][lane][0];
        }
    int trow = tile * 16 + (lane & 15);
    int kb = (lane >> 4) << 3;
    f32x4 acc[2] = {(f32x4){0.f,0.f,0.f,0.f}, (f32x4){0.f,0.f,0.f,0.f}};
    #pragma unroll
    for (int kt = 0; kt < 2; ++kt) {
        float4 p0 = *(const float4*)&rowbuf[trow][kt * 32 + kb];
        float4 p1 = *(const float4*)&rowbuf[trow][kt * 32 + kb + 4];
        float v[8] = {p0.x, p0.y, p0.z, p0.w, p1.x, p1.y, p1.z, p1.w};
        f16x8 ah, al;
        #pragma unroll
        for (int j = 0; j < 8; ++j) {
            _Float16 h = (_Float16)v[j];
            ah[j] = h;
            al[j] = (_Float16)(v[j] - (float)h);
        }
        #pragma unroll
        for (int c2 = 0; c2 < 2; ++c2) {
            acc[c2] = __builtin_amdgcn_mfma_f32_16x16x32_f16(ah, Bh[kt][c2], acc[c2], 0, 0, 0);
            acc[c2] = __builtin_amdgcn_mfma_f32_16x16x32_f16(al, Bh[kt][c2], acc[c2], 0, 0, 0);
            acc[c2] = __builtin_amdgcn_mfma_f32_16x16x32_f16(ah, Bl[kt][c2], acc[c2], 0, 0, 0);
        }
    }
    int rb = tile * 16 + ((lane >> 4) << 2);
    int cb = lane & 15;
    #pragma unroll
    for (int r = 0; r < 4; ++r) {
        int node2 = blockIdx.x * 64 + rb + r;
        if (node2 < n) {
            float d = dinv[node2];
            #pragma unroll
            for (int c2 = 0; c2 < 2; ++c2)
                out[(size_t)node2 * 64 + (ct0 + c2) * 16 + cb] =
                    __float2half(acc[c2][r] * d);
        }
    }
}

// ---------------- fused final: agg + ELU + FC(64->16) MFMA + softmax ----------------
__global__ __launch_bounds__(512, 4) void agg_fc(const __half* __restrict__ T,
                                                 const int* __restrict__ offs,
                                                 const int* __restrict__ cnt,
                                                 const int* __restrict__ csr_src,
                                                 const float* __restrict__ dinv,
                                                 const float* __restrict__ bias,
                                                 const float* __restrict__ fcw,
                                                 const float* __restrict__ fcb,
                                                 float* __restrict__ out, int n) {
    __shared__ _Float16 bhi[2][64][8];      // 2 KB
    __shared__ _Float16 blo[2][64][8];
    __shared__ float rowbuf[64][68];
    int tid = threadIdx.x;
    for (int it = 0; it < 2; ++it) {
        int idx = it * 512 + tid;           // 1024 = 64 k * 16 j
        int k = idx >> 4, j16 = idx & 15;
        float w = fcw[idx];
        _Float16 h = (_Float16)w;
        _Float16 lo = (_Float16)(w - (float)h);
        int kt = k >> 5, kr = k & 31;
        int g = kr >> 3, j = kr & 7;
        bhi[kt][g * 16 + j16][j] = h;
        blo[kt][g * 16 + j16][j] = lo;
    }
    int grp = tid >> 3, l8 = tid & 7;
    int node = blockIdx.x * 64 + grp;
    float hA[4] = {0.f, 0.f, 0.f, 0.f};
    float hB[4] = {0.f, 0.f, 0.f, 0.f};
    if (node < n) {
        const u32x4* T4 = (const u32x4*)T;
        float ax[8] = {0,0,0,0,0,0,0,0};
        float ay[8] = {0,0,0,0,0,0,0,0};
        {
            u32x4 q = T4[node * 8 + l8];
            #pragma unroll
            for (int u = 0; u < 4; ++u) {
                float2 f = cvt2(q[u]);
                ax[u] += f.x; ax[u + 4] += f.y;
            }
        }
        int e0 = offs[node];
        int e1 = e0 + ((cnt[node] + 7) & ~7);
        #pragma unroll 1
        for (int e = e0; e < e1; e += 8) {
            i32x4 sa = __builtin_nontemporal_load((const i32x4*)(csr_src + e));
            i32x4 sb = __builtin_nontemporal_load((const i32x4*)(csr_src + e + 4));
            u32x4 q0 = T4[sa.x * 8 + l8];
            u32x4 q1 = T4[sa.y * 8 + l8];
            u32x4 q2 = T4[sa.z * 8 + l8];
            u32x4 q3 = T4[sa.w * 8 + l8];
            u32x4 q4 = T4[sb.x * 8 + l8];
            u32x4 q5 = T4[sb.y * 8 + l8];
            u32x4 q6 = T4[sb.z * 8 + l8];
            u32x4 q7 = T4[sb.w * 8 + l8];
            #pragma unroll
            for (int u = 0; u < 4; ++u) {
                float2 f0 = cvt2(q0[u]);
                float2 f1 = cvt2(q1[u]);
                float2 f2 = cvt2(q2[u]);
                float2 f3 = cvt2(q3[u]);
                float2 f4 = cvt2(q4[u]);
                float2 f5 = cvt2(q5[u]);
                float2 f6 = cvt2(q6[u]);
                float2 f7 = cvt2(q7[u]);
                ax[u]     += (f0.x + f1.x) + (f2.x + f3.x);
                ay[u]     += (f4.x + f5.x) + (f6.x + f7.x);
                ax[u + 4] += (f0.y + f1.y) + (f2.y + f3.y);
                ay[u + 4] += (f4.y + f5.y) + (f6.y + f7.y);
            }
        }
        float di = dinv[node];
        float4 b0 = *(const float4*)(bias + l8 * 8);
        float4 b1 = *(const float4*)(bias + l8 * 8 + 4);
        float bb[8] = {b0.x, b0.y, b0.z, b0.w, b1.x, b1.y, b1.z, b1.w};
        #pragma unroll
        for (int u = 0; u < 4; ++u) {
            hA[u] = eluf((ax[u] + ay[u]) * di + bb[2 * u]);
            hB[u] = eluf((ax[u + 4] + ay[u + 4]) * di + bb[2 * u + 1]);
        }
    }
    float4 r0 = make_float4(hA[0], hB[0], hA[1], hB[1]);
    float4 r1 = make_float4(hA[2], hB[2], hA[3], hB[3]);
    *(float4*)&rowbuf[grp][l8 * 8] = r0;
    *(float4*)&rowbuf[grp][l8 * 8 + 4] = r1;
    __syncthreads();

    int wv = tid >> 6, lane = tid & 63;
    if (wv >= 4) return;                    // 4 waves cover the 4 row-tiles
    f16x8 Bh[2], Bl[2];
    #pragma unroll
    for (int kt = 0; kt < 2; ++kt) {
        Bh[kt] = *(const f16x8*)&bhi[kt][lane][0];
        Bl[kt] = *(const f16x8*)&blo[kt][lane][0];
    }
    int trow = wv * 16 + (lane & 15);
    int kb = (lane >> 4) << 3;
    f32x4 acc = (f32x4){0.f, 0.f, 0.f, 0.f};
    #pragma unroll
    for (int kt = 0; kt < 2; ++kt) {
        float4 p0 = *(const float4*)&rowbuf[trow][kt * 32 + kb];
        float4 p1 = *(const float4*)&rowbuf[trow][kt * 32 + kb + 4];
        float v[8] = {p0.x, p0.y, p0.z, p0.w, p1.x, p1.y, p1.z, p1.w};
        f16x8 ah, al;
        #pragma unroll
        for (int j = 0; j < 8; ++j) {
            _Float16 h = (_Float16)v[j];
            ah[j] = h;
            al[j] = (_Float16)(v[j] - (float)h);
        }
        acc = __builtin_amdgcn_mfma_f32_16x16x32_f16(ah, Bh[kt], acc, 0, 0, 0);
        acc = __builtin_amdgcn_mfma_f32_16x16x32_f16(al, Bh[kt], acc, 0, 0, 0);
        acc = __builtin_amdgcn_mfma_f32_16x16x32_f16(ah, Bl[kt], acc, 0, 0, 0);
    }
    float bj = fcb[lane & 15];
    #pragma unroll
    for (int r = 0; r < 4; ++r) {
        float o = acc[r] + bj;
        float m = o;
        #pragma unroll
        for (int d = 8; d; d >>= 1) m = fmaxf(m, __shfl_xor(m, d, 64));
        float ex = expf(o - m);
        float s = ex;
        #pragma unroll
        for (int d = 8; d; d >>= 1) s += __shfl_xor(s, d, 64);
        int node2 = blockIdx.x * 64 + wv * 16 + ((lane >> 4) << 2) + r;
        if (node2 < n) out[(size_t)node2 * 16 + (lane & 15)] = ex / s;
    }
}

extern "C" void kernel_launch(void* const* d_in, const int* in_sizes, int n_in,
                              void* d_out, int out_size, void* d_ws, size_t ws_size,
                              hipStream_t stream) {
    const float* x   = (const float*)d_in[0];
    const int*   ei  = (const int*)d_in[1];
    const float* w0  = (const float*)d_in[2];
    const float* b0  = (const float*)d_in[3];
    const float* w1  = (const float*)d_in[4];
    const float* b1  = (const float*)d_in[5];
    const float* w2  = (const float*)d_in[6];
    const float* b2  = (const float*)d_in[7];
    const float* fcw = (const float*)d_in[8];
    const float* fcb = (const float*)d_in[9];
    float* out = (float*)d_out;

    const int N = in_sizes[0] / 128;
    const int E = in_sizes[1] / 2;
    const int* src = ei;
    const int* dst = ei + E;
    const int csr_cap = E + 8 * N + 8;

    char* p = (char*)d_ws;
    auto take = [&](size_t bytes) {
        char* q = p;
        p += (bytes + 255) & ~(size_t)255;
        return q;
    };
    int*    counts  = (int*)take((size_t)(N + 1) * 4);  // counts[N] = gtotal
    int*    gtotal  = counts + N;
    int*    offs    = (int*)take((size_t)N * 4);
    int*    cursor  = (int*)take((size_t)N * 4);
    float*  dinv    = (float*)take((size_t)N * 4);
    int*    csr_src = (int*)take((size_t)csr_cap * 4);
    __half* tbufA   = (__half*)take((size_t)(N + 1) * 64 * 2);
    __half* tbufB   = (__half*)take((size_t)(N + 1) * 64 * 2);

    hipMemsetAsync(counts, 0, (size_t)(N + 1) * 4, stream);

    deg_kernel<<<(E + 255) / 256, 256, 0, stream>>>(dst, counts, E);
    alloc_kernel<<<(N + 255) / 256, 256, 0, stream>>>(counts, gtotal, offs, cursor,
                                                      dinv, csr_src, N);
    int winSize = (N + NWIN - 1) / NWIN;
    scatter_kernel<<<1024, 256, 0, stream>>>(src, dst, cursor, csr_src, E, winSize);

    int nTiles = (N + 15) / 16;
    int agg_grid = (N + 63) / 64;

    mm128_mfma<<<(nTiles + 3) / 4, 256, 0, stream>>>(x, w0, dinv, tbufA, N, nTiles);
    agg_mm<<<agg_grid, 512, 0, stream>>>(tbufA, offs, counts, csr_src,
                                         dinv, b0, w1, tbufB, N);
    agg_mm<<<agg_grid, 512, 0, stream>>>(tbufB, offs, counts, csr_src,
                                         dinv, b1, w2, tbufA, N);
    agg_fc<<<agg_grid, 512, 0, stream>>>(tbufA, offs, counts, csr_src,
                                         dinv, b2, fcw, fcb, out, N);
}